// Round 1
// baseline (519.686 us; speedup 1.0000x reference)
//
#include <hip/hip_runtime.h>
#include <cstdint>
#include <cstddef>

#define BB 8
#define TT 2048
#define CC 2048
#define EE 32
#define HH 64
#define KC 4

// ---------------- kernel 1: deterministic partial sums for token mean ----------------
// grid (B*C/256, 8), block 256. partial[chunk][b*C+c] = sum over 256 tokens.
__global__ void k_seqsum(const float* __restrict__ hs, float* __restrict__ partial) {
    int idx = blockIdx.x * 256 + threadIdx.x;       // 0..B*C-1
    int chunk = blockIdx.y;                          // 0..7
    int b = idx / CC, c = idx % CC;
    const float* p = hs + (size_t)b * TT * CC + (size_t)chunk * (TT / 8) * CC + c;
    float s = 0.f;
    #pragma unroll 4
    for (int t = 0; t < TT / 8; ++t) s += p[(size_t)t * CC];
    partial[(size_t)chunk * (BB * CC) + idx] = s;
}

// ---------------- kernel 2: gating -> routing (B,E) ----------------
__device__ __forceinline__ float block_reduce_sum(float v, float* red, int tid) {
    red[tid] = v;
    __syncthreads();
    for (int s = 128; s > 0; s >>= 1) {
        if (tid < s) red[tid] += red[tid + s];
        __syncthreads();
    }
    float r = red[0];
    __syncthreads();
    return r;
}

__global__ void k_gating(const float* __restrict__ partial, const float* __restrict__ sim,
                         const float* __restrict__ gates, float* __restrict__ routing) {
    __shared__ float sr[CC];
    __shared__ float red[256];
    __shared__ float logits_s[EE];
    int b = blockIdx.x, tid = threadIdx.x;
    for (int c = tid; c < CC; c += 256) {
        float s = 0.f;
        #pragma unroll
        for (int ch = 0; ch < 8; ++ch) s += partial[(size_t)ch * (BB * CC) + b * CC + c];
        sr[c] = s * (1.0f / (float)TT);
    }
    __syncthreads();
    float ss = 0.f;
    for (int c = tid; c < CC; c += 256) ss += sr[c] * sr[c];
    float srnorm2 = block_reduce_sum(ss, red, tid);
    float inv_srnorm = rsqrtf(srnorm2);
    for (int e = 0; e < EE; ++e) {
        float d = 0.f, n = 0.f;
        for (int c = tid; c < CC; c += 256) {
            float v = sim[(size_t)c * EE + e];
            d += sr[c] * v;
            n += v * v;
        }
        float dt = block_reduce_sum(d, red, tid);
        float nt = block_reduce_sum(n, red, tid);
        if (tid == 0) {
            float aff = dt * inv_srnorm * rsqrtf(nt);
            float sg = 1.0f / (1.0f + expf(-gates[e]));
            logits_s[e] = aff - sg;
        }
        __syncthreads();
    }
    if (tid == 0) {
        float gated[EE];
        int mask[EE];
        int nact = 0;
        for (int e = 0; e < EE; ++e) {
            float g = logits_s[e] > 0.f ? logits_s[e] : 0.f;
            gated[e] = g;
            mask[e] = (g > 0.f) ? 1 : 0;
            nact += mask[e];
        }
        if (nact == 0) {
            // top E/2 by logits, descending, stable (strict > keeps lower index on ties)
            int chosen[EE];
            for (int e = 0; e < EE; ++e) chosen[e] = 0;
            for (int k = 0; k < EE / 2; ++k) {
                int best = -1;
                float bv = 0.f;
                for (int e = 0; e < EE; ++e) {
                    if (chosen[e]) continue;
                    if (best < 0 || logits_s[e] > bv) { best = e; bv = logits_s[e]; }
                }
                chosen[best] = 1;
            }
            for (int e = 0; e < EE; ++e) mask[e] = chosen[e];
        }
        float m = -3.402823466e+38f;
        for (int e = 0; e < EE; ++e)
            if (mask[e] && gated[e] > m) m = gated[e];
        float ssum = 0.f;
        float ex[EE];
        for (int e = 0; e < EE; ++e) {
            float v = mask[e] ? expf(gated[e] - m) : 0.f;
            ex[e] = v;
            ssum += v;
        }
        float inv = 1.0f / ssum;
        for (int e = 0; e < EE; ++e) routing[b * EE + e] = ex[e] * inv;
    }
}

// ---------------- kernel 3: routing-weighted weight mix ----------------
// grid (H*C/256, 2): y==0 -> w_v_eff, y==1 -> w_o_dyn. dst[b][h][c] = sum_e r[b][e]*w[e][h][c]
__global__ void k_wmix(const float* __restrict__ w_v, const float* __restrict__ o_w,
                       const float* __restrict__ routing,
                       float* __restrict__ w_v_eff, float* __restrict__ w_o_dyn) {
    __shared__ float r[BB * EE];
    int tid = threadIdx.x;
    if (tid < BB * EE) r[tid] = routing[tid];
    __syncthreads();
    size_t idx = (size_t)blockIdx.x * 256 + tid;    // over H*C
    const float* w = blockIdx.y ? o_w : w_v;
    float* dst = blockIdx.y ? w_o_dyn : w_v_eff;
    float acc[BB];
    #pragma unroll
    for (int b = 0; b < BB; ++b) acc[b] = 0.f;
    for (int e = 0; e < EE; ++e) {
        float v = w[(size_t)e * HH * CC + idx];
        #pragma unroll
        for (int b = 0; b < BB; ++b) acc[b] += r[b * EE + e] * v;
    }
    #pragma unroll
    for (int b = 0; b < BB; ++b) dst[(size_t)b * HH * CC + idx] = acc[b];
}

// ---------------- kernel 4: GEMM1 (split-K): combined = hs @ w_v_eff^T ----------------
// grid (B*T/64, KC), block 256. partialC[kc][b][t][h]
__global__ void k_gemm1(const float* __restrict__ hs, const float* __restrict__ w_v_eff,
                        float* __restrict__ partialC) {
    int bt = blockIdx.x;
    int b = bt / (TT / 64);
    int t0 = (bt % (TT / 64)) * 64;
    int kc = blockIdx.y;
    int k0base = kc * (CC / KC);
    __shared__ float As[64][33];
    __shared__ float Bs[64][33];
    int tid = threadIdx.x;
    int tx = tid & 15, ty = tid >> 4;
    float acc[4][4] = {};
    const float* Ag = hs + (size_t)b * TT * CC + (size_t)t0 * CC;
    const float* Bg = w_v_eff + (size_t)b * HH * CC;
    for (int k0 = k0base; k0 < k0base + CC / KC; k0 += 32) {
        #pragma unroll
        for (int i = 0; i < 8; ++i) {
            int idx = tid + i * 256;
            int rr = idx >> 5, cc2 = idx & 31;
            As[rr][cc2] = Ag[(size_t)rr * CC + k0 + cc2];
            Bs[rr][cc2] = Bg[(size_t)rr * CC + k0 + cc2];
        }
        __syncthreads();
        #pragma unroll
        for (int kk = 0; kk < 32; ++kk) {
            float a[4], bb[4];
            #pragma unroll
            for (int i = 0; i < 4; ++i) a[i] = As[ty * 4 + i][kk];
            #pragma unroll
            for (int j = 0; j < 4; ++j) bb[j] = Bs[tx * 4 + j][kk];
            #pragma unroll
            for (int i = 0; i < 4; ++i)
                #pragma unroll
                for (int j = 0; j < 4; ++j) acc[i][j] += a[i] * bb[j];
        }
        __syncthreads();
    }
    float* Cg = partialC + ((size_t)kc * BB + b) * TT * HH + (size_t)t0 * HH;
    #pragma unroll
    for (int i = 0; i < 4; ++i)
        #pragma unroll
        for (int j = 0; j < 4; ++j)
            Cg[(size_t)(ty * 4 + i) * HH + tx * 4 + j] = acc[i][j];
}

// ---------------- kernel 5: split-K reduce ----------------
__global__ void k_reduce(const float* __restrict__ partialC, float* __restrict__ combined) {
    size_t idx = (size_t)blockIdx.x * 256 + threadIdx.x;
    float s = 0.f;
    #pragma unroll
    for (int kc = 0; kc < KC; ++kc) s += partialC[(size_t)kc * BB * TT * HH + idx];
    combined[idx] = s;
}

// ---------------- kernel 6: GEMM2: out = combined @ w_o_dyn ----------------
// grid (C/64, T/64, B), block 256
__global__ void k_gemm2(const float* __restrict__ combined, const float* __restrict__ w_o_dyn,
                        float* __restrict__ out) {
    int d0 = blockIdx.x * 64;
    int t0 = blockIdx.y * 64;
    int b = blockIdx.z;
    __shared__ float As[64][65];   // As[t][h]
    __shared__ float Bs[64][64];   // Bs[h][d]
    int tid = threadIdx.x;
    int tx = tid & 15, ty = tid >> 4;
    const float* Ag = combined + (size_t)b * TT * HH + (size_t)t0 * HH;
    const float* Bg = w_o_dyn + (size_t)b * HH * CC + d0;
    #pragma unroll
    for (int i = 0; i < 16; ++i) {
        int idx = tid + i * 256;
        int rr = idx >> 6, cc2 = idx & 63;
        As[rr][cc2] = Ag[(size_t)rr * HH + cc2];
        Bs[rr][cc2] = Bg[(size_t)rr * CC + cc2];
    }
    __syncthreads();
    float acc[4][4] = {};
    #pragma unroll
    for (int kk = 0; kk < 64; ++kk) {
        float a[4], bb[4];
        #pragma unroll
        for (int i = 0; i < 4; ++i) a[i] = As[ty * 4 + i][kk];
        #pragma unroll
        for (int j = 0; j < 4; ++j) bb[j] = Bs[kk][tx * 4 + j];
        #pragma unroll
        for (int i = 0; i < 4; ++i)
            #pragma unroll
            for (int j = 0; j < 4; ++j) acc[i][j] += a[i] * bb[j];
    }
    float* Og = out + (size_t)b * TT * CC + (size_t)t0 * CC + d0;
    #pragma unroll
    for (int i = 0; i < 4; ++i) {
        float4 v = make_float4(acc[i][0], acc[i][1], acc[i][2], acc[i][3]);
        *(float4*)&Og[(size_t)(ty * 4 + i) * CC + tx * 4] = v;
    }
}

extern "C" void kernel_launch(void* const* d_in, const int* in_sizes, int n_in,
                              void* d_out, int out_size, void* d_ws, size_t ws_size,
                              hipStream_t stream) {
    const float* hs    = (const float*)d_in[0];   // (B,T,C)
    const float* sim   = (const float*)d_in[1];   // (C,E)
    const float* gates = (const float*)d_in[2];   // (E,)
    // d_in[3] = w_q, d_in[4] = w_k: dead inputs (seq_len-1 SDPA == identity on v)
    const float* w_v   = (const float*)d_in[5];   // (E,H,C)
    const float* o_w   = (const float*)d_in[6];   // (E,H,C)
    float* out = (float*)d_out;
    float* ws  = (float*)d_ws;

    // workspace layout (floats)
    const size_t OFF_PARTSEQ = 0;                              // 8*B*C      = 131072
    const size_t OFF_ROUTING = 131072;                         // B*E        = 256
    const size_t OFF_WVEFF   = 131328;                         // B*H*C      = 1048576
    const size_t OFF_WODYN   = 1179904;                        // B*H*C      = 1048576
    const size_t OFF_COMB    = 2228480;                        // B*T*H      = 1048576
    const size_t OFF_PARTC   = 3277056;                        // KC*B*T*H   = 4194304
    const size_t TOTAL_FLOATS = OFF_PARTC + (size_t)KC * BB * TT * HH;

    float* partial_seq = ws + OFF_PARTSEQ;
    float* routing     = ws + OFF_ROUTING;
    float* w_v_eff     = ws + OFF_WVEFF;
    float* w_o_dyn     = ws + OFF_WODYN;
    float* combined    = ws + OFF_COMB;
    float* partialC;
    if (ws_size >= TOTAL_FLOATS * sizeof(float)) {
        partialC = ws + OFF_PARTC;
    } else {
        // overlay split-K partials into d_out; k_gemm2 fully overwrites out afterwards
        partialC = out;
    }

    hipLaunchKernelGGL(k_seqsum, dim3(BB * CC / 256, 8), dim3(256), 0, stream, hs, partial_seq);
    hipLaunchKernelGGL(k_gating, dim3(BB), dim3(256), 0, stream, partial_seq, sim, gates, routing);
    hipLaunchKernelGGL(k_wmix, dim3(HH * CC / 256, 2), dim3(256), 0, stream,
                       w_v, o_w, routing, w_v_eff, w_o_dyn);
    hipLaunchKernelGGL(k_gemm1, dim3(BB * (TT / 64), KC), dim3(256), 0, stream,
                       hs, w_v_eff, partialC);
    hipLaunchKernelGGL(k_reduce, dim3(BB * TT * HH / 256), dim3(256), 0, stream,
                       partialC, combined);
    hipLaunchKernelGGL(k_gemm2, dim3(CC / 64, TT / 64, BB), dim3(256), 0, stream,
                       combined, w_o_dyn, out);
}

// Round 2
// 356.912 us; speedup vs baseline: 1.4561x; 1.4561x over previous
//
#include <hip/hip_runtime.h>
#include <hip/hip_bf16.h>
#include <cstdint>
#include <cstddef>

#define BB 8
#define TT 2048
#define CC 2048
#define EE 32
#define HH 64

typedef __bf16 v8bf __attribute__((ext_vector_type(8)));
typedef float v4f __attribute__((ext_vector_type(4)));

// async global->LDS, 16B per lane; LDS dest must be wave-uniform base (+lane*16 by HW)
#define GLOAD16(gp, lp)                                                              \
  __builtin_amdgcn_global_load_lds((const __attribute__((address_space(1))) void*)(gp), \
                                   (__attribute__((address_space(3))) void*)(lp), 16, 0, 0)

// ---------------- kernel 1: token partial sums + bf16 conversion (one pass over hs) ----
// grid (B*C/256, 8), block 256
__global__ void k_convsum(const float* __restrict__ hs, __hip_bfloat16* __restrict__ hsb,
                          float* __restrict__ partial) {
    int idx = blockIdx.x * 256 + threadIdx.x;        // 0..B*C-1
    int chunk = blockIdx.y;
    int b = idx >> 11, c = idx & (CC - 1);
    const float* p = hs + (size_t)b * TT * CC + (size_t)chunk * (TT / 8) * CC + c;
    __hip_bfloat16* q = hsb + (size_t)b * TT * CC + (size_t)chunk * (TT / 8) * CC + c;
    float s = 0.f;
    #pragma unroll 4
    for (int t = 0; t < TT / 8; ++t) {
        float v = p[(size_t)t * CC];
        s += v;
        q[(size_t)t * CC] = __float2bfloat16(v);
    }
    partial[(size_t)chunk * (BB * CC) + idx] = s;
}

// ---------------- kernel 2: affinity logits, one block per (e,b) ----------------
// note: 1/T mean factor cancels in the cosine normalization -> skipped
__global__ void k_affinity(const float* __restrict__ partial, const float* __restrict__ sim,
                           const float* __restrict__ gates, float* __restrict__ logits) {
    __shared__ float red[256];
    int e = blockIdx.x, b = blockIdx.y, tid = threadIdx.x;
    float d = 0.f, n = 0.f, m2 = 0.f;
    for (int c = tid; c < CC; c += 256) {
        float sr = 0.f;
        #pragma unroll
        for (int ch = 0; ch < 8; ++ch) sr += partial[(size_t)ch * (BB * CC) + b * CC + c];
        float sv = sim[(size_t)c * EE + e];
        d += sr * sv; n += sv * sv; m2 += sr * sr;
    }
    red[tid] = d; __syncthreads();
    for (int s = 128; s > 0; s >>= 1) { if (tid < s) red[tid] += red[tid + s]; __syncthreads(); }
    d = red[0]; __syncthreads();
    red[tid] = n; __syncthreads();
    for (int s = 128; s > 0; s >>= 1) { if (tid < s) red[tid] += red[tid + s]; __syncthreads(); }
    n = red[0]; __syncthreads();
    red[tid] = m2; __syncthreads();
    for (int s = 128; s > 0; s >>= 1) { if (tid < s) red[tid] += red[tid + s]; __syncthreads(); }
    m2 = red[0];
    if (tid == 0) {
        float aff = d * rsqrtf(n) * rsqrtf(m2);
        float sg = 1.0f / (1.0f + expf(-gates[e]));
        logits[b * EE + e] = aff - sg;
    }
}

// ---------------- kernel 3: mask/fallback/softmax -> routing (B,E) ----------------
__global__ void k_route(const float* __restrict__ logits, float* __restrict__ routing) {
    int b = threadIdx.x;
    if (b >= BB) return;
    float lg[EE], gated[EE];
    int mask[EE];
    int nact = 0;
    for (int e = 0; e < EE; ++e) {
        lg[e] = logits[b * EE + e];
        float g = lg[e] > 0.f ? lg[e] : 0.f;
        gated[e] = g;
        mask[e] = (g > 0.f) ? 1 : 0;
        nact += mask[e];
    }
    if (nact == 0) {
        int chosen[EE];
        for (int e = 0; e < EE; ++e) chosen[e] = 0;
        for (int k = 0; k < EE / 2; ++k) {   // stable top-k: strict > keeps lowest index on ties
            int best = -1; float bv = 0.f;
            for (int e = 0; e < EE; ++e) {
                if (chosen[e]) continue;
                if (best < 0 || lg[e] > bv) { best = e; bv = lg[e]; }
            }
            chosen[best] = 1;
        }
        for (int e = 0; e < EE; ++e) mask[e] = chosen[e];
    }
    float m = -3.402823466e+38f;
    for (int e = 0; e < EE; ++e)
        if (mask[e] && gated[e] > m) m = gated[e];
    float ssum = 0.f; float ex[EE];
    for (int e = 0; e < EE; ++e) {
        float v = mask[e] ? expf(gated[e] - m) : 0.f;
        ex[e] = v; ssum += v;
    }
    float inv = 1.0f / ssum;
    for (int e = 0; e < EE; ++e) routing[b * EE + e] = ex[e] * inv;
}

// ---------------- kernel 4: routing-weighted weight mix -> bf16 ----------------
// grid (H*C/256, 2), block 256. y==0 -> w_v_eff, y==1 -> w_o_dyn
__global__ void k_wmix(const float* __restrict__ w_v, const float* __restrict__ o_w,
                       const float* __restrict__ routing,
                       __hip_bfloat16* __restrict__ wv_eff, __hip_bfloat16* __restrict__ wo_eff) {
    __shared__ float r[BB * EE];
    int tid = threadIdx.x;
    r[tid] = routing[tid];          // BB*EE == 256 == blockDim
    __syncthreads();
    size_t idx = (size_t)blockIdx.x * 256 + tid;
    const float* w = blockIdx.y ? o_w : w_v;
    __hip_bfloat16* dst = blockIdx.y ? wo_eff : wv_eff;
    float acc[BB] = {};
    for (int e = 0; e < EE; ++e) {
        float v = w[(size_t)e * HH * CC + idx];
        #pragma unroll
        for (int b = 0; b < BB; ++b) acc[b] += r[b * EE + e] * v;
    }
    #pragma unroll
    for (int b = 0; b < BB; ++b) dst[(size_t)b * HH * CC + idx] = __float2bfloat16(acc[b]);
}

// ---------------- kernel 5: GEMM1 bf16 MFMA: partialC[kc] = hs_bf16 @ w_v_eff^T ----------
// grid (T/64, 2, B), block 256. NT layout: both A and B rows are [row][K] contiguous.
// XOR swizzle: chunk (row, c) of a 64-row x 64-col bf16 tile lives at LDS slot
// row*8 + (c ^ (row&7)) (16B chunks) -> conflict-free ds_read_b128 at BK=64 while
// satisfying global_load_lds's linear lane->LDS constraint.
__global__ __launch_bounds__(256) void k_gemm1(const __hip_bfloat16* __restrict__ A,
                                               const __hip_bfloat16* __restrict__ Bw,
                                               float* __restrict__ partialC) {
    __shared__ __align__(16) __hip_bfloat16 Asm[64 * 64];
    __shared__ __align__(16) __hip_bfloat16 Bsm[64 * 64];
    int tid = threadIdx.x;
    int t0 = blockIdx.x * 64;
    int kc = blockIdx.y;
    int b  = blockIdx.z;
    const __hip_bfloat16* Ag = A + (size_t)b * TT * CC + (size_t)t0 * CC;
    const __hip_bfloat16* Bg = Bw + (size_t)b * HH * CC;
    int wv = tid >> 6, lane = tid & 63, lm = lane & 15, quad = lane >> 4;
    int L0 = tid, L1 = tid + 256;
    int row0 = L0 >> 3, c0 = ((L0 & 7) ^ (row0 & 7)) * 8;
    int row1 = L1 >> 3, c1 = ((L1 & 7) ^ (row1 & 7)) * 8;
    char* AsmB = (char*)Asm;
    char* BsmB = (char*)Bsm;
    int ldsoff0 = (wv * 64 + lane) * 16;        // == L0*16, wave-uniform base + lane*16
    int ldsoff1 = (256 + wv * 64 + lane) * 16;  // == L1*16
    v4f acc[4] = {};
    int kend = kc * (CC / 2) + CC / 2;
    for (int kk0 = kc * (CC / 2); kk0 < kend; kk0 += 64) {
        GLOAD16(Ag + (size_t)row0 * CC + kk0 + c0, AsmB + ldsoff0);
        GLOAD16(Ag + (size_t)row1 * CC + kk0 + c1, AsmB + ldsoff1);
        GLOAD16(Bg + (size_t)row0 * CC + kk0 + c0, BsmB + ldsoff0);
        GLOAD16(Bg + (size_t)row1 * CC + kk0 + c1, BsmB + ldsoff1);
        __syncthreads();
        int arow = wv * 16 + lm;
        #pragma unroll
        for (int s = 0; s < 2; ++s) {
            v8bf a = *(const v8bf*)(AsmB + (arow * 8 + ((s * 4 + quad) ^ (arow & 7))) * 16);
            #pragma unroll
            for (int j = 0; j < 4; ++j) {
                int brow = j * 16 + lm;
                v8bf bb = *(const v8bf*)(BsmB + (brow * 8 + ((s * 4 + quad) ^ (brow & 7))) * 16);
                acc[j] = __builtin_amdgcn_mfma_f32_16x16x32_bf16(a, bb, acc[j], 0, 0, 0);
            }
        }
        __syncthreads();
    }
    float* Cp = partialC + ((size_t)kc * BB + b) * TT * HH + (size_t)t0 * HH;
    #pragma unroll
    for (int j = 0; j < 4; ++j)
        #pragma unroll
        for (int r2 = 0; r2 < 4; ++r2)
            Cp[(size_t)(wv * 16 + quad * 4 + r2) * HH + j * 16 + lm] = acc[j][r2];
}

// ---------------- kernel 6: split-K reduce -> combined bf16 ----------------
__global__ void k_reduce(const float* __restrict__ pC, __hip_bfloat16* __restrict__ comb) {
    size_t i = (size_t)blockIdx.x * 256 + threadIdx.x;
    comb[i] = __float2bfloat16(pC[i] + pC[i + (size_t)BB * TT * HH]);
}

// ---------------- kernel 7: GEMM2 bf16 MFMA: out = combined @ w_o_dyn ----------------
// grid (C/64, T/64, B), block 256. K=64 single-shot; B staged transposed with pad 72.
__global__ __launch_bounds__(256) void k_gemm2(const __hip_bfloat16* __restrict__ comb,
                                               const __hip_bfloat16* __restrict__ Wo,
                                               float* __restrict__ out) {
    __shared__ __align__(16) __hip_bfloat16 As[64 * 72];
    __shared__ __align__(16) __hip_bfloat16 Bs[64 * 72];
    int tid = threadIdx.x;
    int d0 = blockIdx.x * 64, t0 = blockIdx.y * 64, b = blockIdx.z;
    const __hip_bfloat16* Ag = comb + (size_t)b * TT * HH + (size_t)t0 * HH;
    const __hip_bfloat16* Bg = Wo + (size_t)b * HH * CC + d0;
    #pragma unroll
    for (int r = 0; r < 2; ++r) {              // A tile: [t][h] rows contiguous
        int L = tid + r * 256;
        int row = L >> 3, c = (L & 7) * 8;
        *(int4*)&As[row * 72 + c] = *(const int4*)&Ag[row * 64 + c];
    }
    #pragma unroll
    for (int i = 0; i < 16; ++i) {             // B tile transposed: Bs[d][h] = Wo[h][d0+d]
        int e2 = tid + i * 256;
        int h = e2 >> 6, d = e2 & 63;
        Bs[d * 72 + h] = Bg[(size_t)h * CC + d];
    }
    __syncthreads();
    int wv = tid >> 6, lane = tid & 63, lm = lane & 15, quad = lane >> 4;
    v4f acc[4] = {};
    #pragma unroll
    for (int s = 0; s < 2; ++s) {
        v8bf a = *(const v8bf*)&As[(wv * 16 + lm) * 72 + s * 32 + quad * 8];
        #pragma unroll
        for (int j = 0; j < 4; ++j) {
            v8bf bb = *(const v8bf*)&Bs[(j * 16 + lm) * 72 + s * 32 + quad * 8];
            acc[j] = __builtin_amdgcn_mfma_f32_16x16x32_bf16(a, bb, acc[j], 0, 0, 0);
        }
    }
    float* Og = out + (size_t)b * TT * CC + (size_t)t0 * CC + d0;
    #pragma unroll
    for (int j = 0; j < 4; ++j)
        #pragma unroll
        for (int r2 = 0; r2 < 4; ++r2)
            Og[(size_t)(wv * 16 + quad * 4 + r2) * CC + j * 16 + lm] = acc[j][r2];
}

extern "C" void kernel_launch(void* const* d_in, const int* in_sizes, int n_in,
                              void* d_out, int out_size, void* d_ws, size_t ws_size,
                              hipStream_t stream) {
    const float* hs    = (const float*)d_in[0];   // (B,T,C)
    const float* sim   = (const float*)d_in[1];   // (C,E)
    const float* gates = (const float*)d_in[2];   // (E,)
    // d_in[3]=w_q, d_in[4]=w_k: dead (seq_len-1 SDPA == identity on v)
    const float* w_v   = (const float*)d_in[5];   // (E,H,C)
    const float* o_w   = (const float*)d_in[6];   // (E,H,C)
    float* out = (float*)d_out;
    float* ws  = (float*)d_ws;

    // workspace layout (float units)
    size_t o = 0;
    float* partial = ws + o;                         o += (size_t)8 * BB * CC;       // 131072
    float* logits  = ws + o;                         o += BB * EE;                   // 256
    float* routing = ws + o;                         o += BB * EE;                   // 256
    float* partialC = ws + o;                        o += (size_t)2 * BB * TT * HH;  // 2097152
    __hip_bfloat16* comb = (__hip_bfloat16*)(ws + o); o += (size_t)BB * TT * HH / 2;
    __hip_bfloat16* wve  = (__hip_bfloat16*)(ws + o); o += (size_t)BB * HH * CC / 2;
    __hip_bfloat16* woe  = (__hip_bfloat16*)(ws + o); o += (size_t)BB * HH * CC / 2;
    size_t f_hsb = (size_t)BB * TT * CC / 2;         // 67 MB as floats/2
    bool big = ws_size >= (o + f_hsb) * sizeof(float);
    // small-ws fallback: hs_bf16 overlays the front of d_out (67 of 134 MB);
    // safe because k_gemm2 never reads d_out and fully overwrites it at the end.
    __hip_bfloat16* hsb = big ? (__hip_bfloat16*)(ws + o) : (__hip_bfloat16*)d_out;

    hipLaunchKernelGGL(k_convsum, dim3(BB * CC / 256, 8), dim3(256), 0, stream,
                       hs, hsb, partial);
    hipLaunchKernelGGL(k_affinity, dim3(EE, BB), dim3(256), 0, stream,
                       partial, sim, gates, logits);
    hipLaunchKernelGGL(k_route, dim3(1), dim3(64), 0, stream, logits, routing);
    hipLaunchKernelGGL(k_wmix, dim3(HH * CC / 256, 2), dim3(256), 0, stream,
                       w_v, o_w, routing, wve, woe);
    hipLaunchKernelGGL(k_gemm1, dim3(TT / 64, 2, BB), dim3(256), 0, stream,
                       hsb, wve, partialC);
    hipLaunchKernelGGL(k_reduce, dim3(BB * TT * HH / 256), dim3(256), 0, stream,
                       partialC, comb);
    hipLaunchKernelGGL(k_gemm2, dim3(CC / 64, TT / 64, BB), dim3(256), 0, stream,
                       comb, woe, out);
}